// Round 1
// 396.423 us; speedup vs baseline: 1.0876x; 1.0876x over previous
//
#include <hip/hip_runtime.h>

#define IN_F 4096
#define OUT_F 4096
#define GS 128

// ---- GEMM geometry: 256x256 tile, BK=128 i8, 8 waves (2M x 4N), 512 thr ----
#define BM 256
#define BN 256
#define BKB 128                 // K-bytes (= i8 elements) per K-tile
#define NT (IN_F / BKB)         // 32 K-tiles
#define BUFB (BM * BKB)         // 32768 B per buffer per matrix

typedef int i32x4 __attribute__((ext_vector_type(4)));

typedef __attribute__((address_space(1))) void void_g;
typedef __attribute__((address_space(3))) void void_l;

// Async global->LDS, 16B per lane. LDS dest = wave-uniform base + lane*16.
__device__ __forceinline__ void async_copy16(void* lds, const void* g) {
  __builtin_amdgcn_global_load_lds((const void_g*)g, (void_l*)lds, 16, 0, 0);
}

// Stage one block-wide 8KB chunk (64 rows x 128B) of `mat` K-tile k0 into LDS.
// LDS write is linear: lane d = rowbase*128 + tid*16. Source is pre-swizzled
// (st_16x32: byte ^= ((byte>>9)&1)<<5) so swizzled READS see logical data.
__device__ __forceinline__ void stage_g(signed char* region, int rowbase,
                                        const signed char* mat, int k0,
                                        int wave, int growl, int gcolb) {
  async_copy16(region + rowbase * BKB + wave * 1024,
               mat + (size_t)(rowbase + growl) * IN_F + k0 + gcolb);
}

// inv[perm[i]] = i
__global__ void invperm_kernel(const int* __restrict__ perm, int* __restrict__ inv) {
  int i = blockIdx.x * blockDim.x + threadIdx.x;
  inv[perm[i]] = i;
}

// Fused pre-processing: blocks [0,M) per-token int8 x-quant; blocks [M,M+OUT_F)
// dequant+perm+quant of W rows. Independent work; fused to overlap + drop a launch.
__global__ __launch_bounds__(256) void prep_kernel(
    const float* __restrict__ x,
    unsigned int* __restrict__ xq4,   // [M][IN_F/4]
    float* __restrict__ sx,           // [M]
    const int* __restrict__ wp,       // [OUT_F][IN_F/2]
    const float* __restrict__ wsc,    // [OUT_F][IN_F/GS]
    const int* __restrict__ inv,      // [IN_F]
    unsigned int* __restrict__ wq4,   // [OUT_F][IN_F/4]
    float* __restrict__ sw,           // [OUT_F]
    int M)
{
  __shared__ unsigned int prow[IN_F / 2];  // 8 KB (dequant path)
  __shared__ float srow[IN_F / GS];
  __shared__ float red[256];
  const int tid = threadIdx.x;
  const int b = blockIdx.x;

  if (b < M) {
    // ---- per-token x quantization ----
    const float4* x4 = (const float4*)(x + (size_t)b * IN_F);
    float4 v[4];
    float m = 0.f;
#pragma unroll
    for (int i = 0; i < 4; ++i) {
      v[i] = x4[tid + i * 256];
      m = fmaxf(m, fmaxf(fmaxf(fabsf(v[i].x), fabsf(v[i].y)),
                         fmaxf(fabsf(v[i].z), fabsf(v[i].w))));
    }
    red[tid] = m;
    __syncthreads();
#pragma unroll
    for (int s = 128; s > 0; s >>= 1) {
      if (tid < s) red[tid] = fmaxf(red[tid], red[tid + s]);
      __syncthreads();
    }
    const float mx = red[0];
    const float r = 127.0f / mx;
    if (tid == 0) sx[b] = mx * (1.0f / 127.0f);

    unsigned int* orow = xq4 + (size_t)b * (IN_F / 4);
#pragma unroll
    for (int i = 0; i < 4; ++i) {
      int q0 = (int)rintf(v[i].x * r);
      int q1 = (int)rintf(v[i].y * r);
      int q2 = (int)rintf(v[i].z * r);
      int q3 = (int)rintf(v[i].w * r);
      orow[tid + i * 256] = (unsigned)(q0 & 0xFF) | ((unsigned)(q1 & 0xFF) << 8) |
                            ((unsigned)(q2 & 0xFF) << 16) | ((unsigned)(q3 & 0xFF) << 24);
    }
  } else {
    // ---- W row: dequant + act-order permute + int8 re-quant ----
    const int o = b - M;
    const int4* wp4 = (const int4*)(wp + (size_t)o * (IN_F / 2));
    int4* p4 = (int4*)prow;
#pragma unroll
    for (int i = 0; i < 2; ++i)
      p4[tid + i * 256] = wp4[tid + i * 256];
    if (tid < IN_F / GS) srow[tid] = wsc[o * (IN_F / GS) + tid];
    __syncthreads();

    float m = 0.f;
#pragma unroll
    for (int c = 0; c < 8; ++c) {
      const int p = tid + c * 256;
      const unsigned bb = prow[p];
      const float s = srow[p >> 6];
      const float lo = (float)((int)(bb & 0xFu) - 8);
      const float hi = (float)((int)((bb >> 4) & 0xFu) - 8);
      m = fmaxf(m, fmaxf(fabsf(lo), fabsf(hi)) * s);
    }
    red[tid] = m;
    __syncthreads();
#pragma unroll
    for (int s = 128; s > 0; s >>= 1) {
      if (tid < s) red[tid] = fmaxf(red[tid], red[tid + s]);
      __syncthreads();
    }
    const float wmax = red[0];
    const float r = (wmax > 0.f) ? 127.0f / wmax : 0.f;
    if (tid == 0) sw[o] = wmax * (1.0f / 127.0f);

    unsigned int* orow = wq4 + (size_t)o * (IN_F / 4);
    const int4* inv4 = (const int4*)inv;
#pragma unroll
    for (int c = 0; c < 4; ++c) {
      const int p = tid + c * 256;
      const int4 iv = inv4[p];
      unsigned out = 0;
      const int idx[4] = {iv.x, iv.y, iv.z, iv.w};
#pragma unroll
      for (int e = 0; e < 4; ++e) {
        const int ii = idx[e];
        const unsigned wbits = prow[ii >> 1];
        const int n = (int)((wbits >> ((ii & 1) * 4)) & 0xFu) - 8;
        const float v = (float)n * srow[ii >> 7] * r;
        const int q = (int)rintf(v);
        out |= (unsigned)(q & 0xFF) << (e * 8);
      }
      orow[p] = out;
    }
  }
}

// ---- One K-tile of the 8-phase schedule (4 phases here; 2 K-tiles = 8) ----
// Per phase: ds_read frags (buf cur) | issue 2 gloads (buf nxt) | barrier |
// lgkmcnt(0) | setprio(1) 16 MFMA setprio(0) | counted vmcnt (ph1/ph3) | barrier.
// Staging order for tile t+1: B[0:64),B[64:128) @ph0; B[128:192),B[192:256) @ph1;
// A[0:64),A[128:192) @ph2; A[64:128),A[192:256) @ph3.
// Steady state: boundary vmcnt(2) leaves the two late-A chunks in flight into
// phases 0-1 of the next tile; vmcnt(4) at ph1-end forces them before ph2 reads.
template <bool LAST>
__device__ __forceinline__ void gemm_tile(
    const signed char* Ac, const signed char* Bc,
    signed char* An, signed char* Bn,
    const signed char* a_base, const signed char* b_base, int k0n,
    int wave, int wm, int wn, int l16, int quad, int sx5,
    int growl, int gcolb, i32x4 (&acc)[8][4])
{
  i32x4 bq[4][2];   // B frags cached for the whole tile (read at phase 0)
#pragma unroll
  for (int p = 0; p < 4; ++p) {
    if (p == 0) {
#pragma unroll
      for (int j = 0; j < 4; ++j)
#pragma unroll
        for (int ks = 0; ks < 2; ++ks) {
          const int off = (((wn + j * 16 + l16) * BKB) + ks * 64 + quad * 16) ^ sx5;
          bq[j][ks] = *(const i32x4*)(Bc + off);
        }
    }
    i32x4 aq[2][2];
#pragma unroll
    for (int i = 0; i < 2; ++i)
#pragma unroll
      for (int ks = 0; ks < 2; ++ks) {
        const int off = (((wm + p * 32 + i * 16 + l16) * BKB) + ks * 64 + quad * 16) ^ sx5;
        aq[i][ks] = *(const i32x4*)(Ac + off);
      }
    if (!LAST) {
      if (p == 0) {
        stage_g(Bn, 0, b_base, k0n, wave, growl, gcolb);
        stage_g(Bn, 64, b_base, k0n, wave, growl, gcolb);
      } else if (p == 1) {
        stage_g(Bn, 128, b_base, k0n, wave, growl, gcolb);
        stage_g(Bn, 192, b_base, k0n, wave, growl, gcolb);
      } else if (p == 2) {
        stage_g(An, 0, a_base, k0n, wave, growl, gcolb);
        stage_g(An, 128, a_base, k0n, wave, growl, gcolb);
      } else {
        stage_g(An, 64, a_base, k0n, wave, growl, gcolb);
        stage_g(An, 192, a_base, k0n, wave, growl, gcolb);
      }
    }
    __builtin_amdgcn_s_barrier();
    asm volatile("s_waitcnt lgkmcnt(0)" ::: "memory");
    __builtin_amdgcn_sched_barrier(0);   // rule #18: pin MFMA below the wait
    __builtin_amdgcn_s_setprio(1);
#pragma unroll
    for (int i = 0; i < 2; ++i)
#pragma unroll
      for (int j = 0; j < 4; ++j)
#pragma unroll
        for (int ks = 0; ks < 2; ++ks)
          acc[2 * p + i][j] = __builtin_amdgcn_mfma_i32_16x16x64_i8(
              aq[i][ks], bq[j][ks], acc[2 * p + i][j], 0, 0, 0);
    __builtin_amdgcn_s_setprio(0);
    if (p == 1) {
      if (LAST) { asm volatile("s_waitcnt vmcnt(0)" ::: "memory"); }
      else      { asm volatile("s_waitcnt vmcnt(4)" ::: "memory"); }
      __builtin_amdgcn_sched_barrier(0);
    } else if (p == 3 && !LAST) {
      asm volatile("s_waitcnt vmcnt(2)" ::: "memory");
      __builtin_amdgcn_sched_barrier(0);
    }
    __builtin_amdgcn_s_barrier();
  }
}

// C[M][N] = xq(i8) * wq(i8)^T scaled by sx[row]*sw[col] + bias.
// 256^2 8-phase template (T2 swizzle + T3/T4 counted vmcnt + T5 setprio),
// i8 variant: byte-layout identical to the bf16 template (BK=128 B/row,
// two mfma_i32_16x16x64_i8 per fragment at byte offsets 0/64).
__global__ __launch_bounds__(512, 2) void gemm_kernel(
    const signed char* __restrict__ A,
    const signed char* __restrict__ B,
    const float* __restrict__ sx,
    const float* __restrict__ sw,
    const float* __restrict__ bias,
    float* __restrict__ C) {
  __shared__ signed char As[2 * BUFB];  // 64 KB
  __shared__ signed char Bs[2 * BUFB];  // 64 KB

  const int tid  = threadIdx.x;
  const int wave = tid >> 6;
  const int lane = tid & 63;
  const int quad = lane >> 4;
  const int l16  = lane & 15;

  const int bm = blockIdx.y;
  const int bn = blockIdx.x;
  const signed char* a_base = A + (size_t)bm * BM * IN_F;
  const signed char* b_base = B + (size_t)bn * BN * IN_F;

  // per-wave output strip: 128 rows x 64 cols (2M x 4N wave grid)
  const int wm = (wave >> 2) * 128;
  const int wn = (wave & 3) * 64;
  // read-side swizzle: bit9 of (row*128+col) is row bit2 = l16 bit2
  const int sx5 = ((l16 >> 2) & 1) << 5;

  // staging source pre-swizzle: lane LDS byte d = rowbase*128 + tid*16;
  // logical l = d ^ (((d>>9)&1)<<5); bit9 of d comes from tid bit5.
  const int lt    = (tid << 4) ^ (((tid >> 5) & 1) << 5);
  const int growl = lt >> 7;    // row 0..63 within 64-row chunk
  const int gcolb = lt & 127;   // byte col, 16B-aligned

  i32x4 acc[8][4] = {};

  // Prologue: stage tile 0 (same chunk order as steady state), then counted
  // wait: the two late-A chunks may stay in flight into phases 0-1.
  stage_g(Bs, 0, b_base, 0, wave, growl, gcolb);
  stage_g(Bs, 64, b_base, 0, wave, growl, gcolb);
  stage_g(Bs, 128, b_base, 0, wave, growl, gcolb);
  stage_g(Bs, 192, b_base, 0, wave, growl, gcolb);
  stage_g(As, 0, a_base, 0, wave, growl, gcolb);
  stage_g(As, 128, a_base, 0, wave, growl, gcolb);
  stage_g(As, 64, a_base, 0, wave, growl, gcolb);
  stage_g(As, 192, a_base, 0, wave, growl, gcolb);
  asm volatile("s_waitcnt vmcnt(2)" ::: "memory");
  __builtin_amdgcn_sched_barrier(0);
  __builtin_amdgcn_s_barrier();

#pragma unroll 1
  for (int t = 0; t < NT - 1; ++t) {
    const int cur = t & 1;
    const int nxt = cur ^ 1;
    gemm_tile<false>(As + cur * BUFB, Bs + cur * BUFB,
                     As + nxt * BUFB, Bs + nxt * BUFB,
                     a_base, b_base, (t + 1) * BKB,
                     wave, wm, wn, l16, quad, sx5, growl, gcolb, acc);
  }
  gemm_tile<true>(As + ((NT - 1) & 1) * BUFB, Bs + ((NT - 1) & 1) * BUFB,
                  nullptr, nullptr, a_base, b_base, 0,
                  wave, wm, wn, l16, quad, sx5, growl, gcolb, acc);

  // Epilogue: stage scales+bias in LDS (all tile reads drained at last barrier)
  float* sxs = (float*)As;          // 256 floats
  float* sws = sxs + BM;            // 256 floats
  float* bsh = sws + BN;            // 256 floats
  if (tid < BM) {
    sxs[tid] = sx[bm * BM + tid];
  } else {
    const int c = tid - BM;
    sws[c] = sw[bn * BN + c];
    bsh[c] = bias[bn * BN + c];
  }
  __syncthreads();

  // C/D layout: col=lane&15, row=quad*4+reg (dtype-independent, m121-m128)
  const int wm_g = bm * BM + wm;
  const int wn_g = bn * BN + wn;
#pragma unroll
  for (int j = 0; j < 4; ++j) {
    const int col_l = wn + j * 16 + l16;
    const float swv = sws[col_l];
    const float bv  = bsh[col_l];
    const int col = wn_g + j * 16 + l16;
#pragma unroll
    for (int i = 0; i < 8; ++i) {
      const int row_l0 = wm + i * 16 + quad * 4;
      const int row0 = wm_g + i * 16 + quad * 4;
#pragma unroll
      for (int r = 0; r < 4; ++r)
        C[(size_t)(row0 + r) * OUT_F + col] =
            (float)acc[i][j][r] * (sxs[row_l0 + r] * swv) + bv;
    }
  }
}

extern "C" void kernel_launch(void* const* d_in, const int* in_sizes, int n_in,
                              void* d_out, int out_size, void* d_ws, size_t ws_size,
                              hipStream_t stream) {
  const float* x    = (const float*)d_in[0];
  const int*   wp   = (const int*)d_in[1];
  const float* wsc  = (const float*)d_in[2];
  const int*   perm = (const int*)d_in[3];
  const float* bias = (const float*)d_in[4];
  float* out = (float*)d_out;

  const int M = in_sizes[0] / IN_F;   // 8192 tokens

  // ws layout: xq [M][IN_F] i8 | wq [OUT_F][IN_F] i8 | sx [M] | sw [OUT_F] | inv [IN_F]
  signed char* xq = (signed char*)d_ws;
  signed char* wq = xq + (size_t)M * IN_F;
  float* sx = (float*)(wq + (size_t)OUT_F * IN_F);
  float* sw = sx + M;
  int* inv = (int*)(sw + OUT_F);

  invperm_kernel<<<IN_F / 256, 256, 0, stream>>>(perm, inv);

  prep_kernel<<<M + OUT_F, 256, 0, stream>>>(
      x, (unsigned int*)xq, sx, wp, wsc, inv, (unsigned int*)wq, sw, M);

  dim3 grid(OUT_F / BN, M / BM);   // (16, 32)
  gemm_kernel<<<grid, 512, 0, stream>>>(xq, wq, sx, sw, bias, out);
}

// Round 3
// 382.214 us; speedup vs baseline: 1.1280x; 1.0372x over previous
//
#include <hip/hip_runtime.h>

#define IN_F 4096
#define OUT_F 4096
#define GS 128

// ---- GEMM geometry: 256x256 tile, BK=128 i8, 8 waves (2M x 4N), 512 thr ----
#define BM 256
#define BN 256
#define BKB 128                 // K-bytes (= i8 elements) per K-tile
#define NT (IN_F / BKB)         // 32 K-tiles
#define BUFB (BM * BKB)         // 32768 B per buffer per matrix

typedef int i32x4 __attribute__((ext_vector_type(4)));

typedef __attribute__((address_space(1))) void void_g;
typedef __attribute__((address_space(3))) void void_l;

// Async global->LDS, 16B per lane. LDS dest = wave-uniform base + lane*16.
__device__ __forceinline__ void async_copy16(void* lds, const void* g) {
  __builtin_amdgcn_global_load_lds((const void_g*)g, (void_l*)lds, 16, 0, 0);
}

// Stage one block-wide 8KB chunk (64 rows x 128B) of `mat` K-tile k0 into LDS.
// LDS write is linear (lane d = tid*16); global source is pre-swizzled with the
// G4 3-bit XOR (byte ^= (row&7)<<4) so swizzled READS see logical data.
__device__ __forceinline__ void stage_g(signed char* region, int rowbase,
                                        const signed char* mat, int k0,
                                        int wave, int growl, int gcolb) {
  async_copy16(region + rowbase * BKB + wave * 1024,
               mat + (size_t)(rowbase + growl) * IN_F + k0 + gcolb);
}

// inv[perm[i]] = i
__global__ void invperm_kernel(const int* __restrict__ perm, int* __restrict__ inv) {
  int i = blockIdx.x * blockDim.x + threadIdx.x;
  inv[perm[i]] = i;
}

// Fused pre-processing: blocks [0,M) per-token int8 x-quant; blocks [M,M+OUT_F)
// dequant+perm+quant of W rows.
__global__ __launch_bounds__(256) void prep_kernel(
    const float* __restrict__ x,
    unsigned int* __restrict__ xq4,   // [M][IN_F/4]
    float* __restrict__ sx,           // [M]
    const int* __restrict__ wp,       // [OUT_F][IN_F/2]
    const float* __restrict__ wsc,    // [OUT_F][IN_F/GS]
    const int* __restrict__ inv,      // [IN_F]
    unsigned int* __restrict__ wq4,   // [OUT_F][IN_F/4]
    float* __restrict__ sw,           // [OUT_F]
    int M)
{
  __shared__ unsigned int prow[IN_F / 2];  // 8 KB (dequant path)
  __shared__ float srow[IN_F / GS];
  __shared__ float red[256];
  const int tid = threadIdx.x;
  const int b = blockIdx.x;

  if (b < M) {
    // ---- per-token x quantization ----
    const float4* x4 = (const float4*)(x + (size_t)b * IN_F);
    float4 v[4];
    float m = 0.f;
#pragma unroll
    for (int i = 0; i < 4; ++i) {
      v[i] = x4[tid + i * 256];
      m = fmaxf(m, fmaxf(fmaxf(fabsf(v[i].x), fabsf(v[i].y)),
                         fmaxf(fabsf(v[i].z), fabsf(v[i].w))));
    }
    red[tid] = m;
    __syncthreads();
#pragma unroll
    for (int s = 128; s > 0; s >>= 1) {
      if (tid < s) red[tid] = fmaxf(red[tid], red[tid + s]);
      __syncthreads();
    }
    const float mx = red[0];
    const float r = 127.0f / mx;
    if (tid == 0) sx[b] = mx * (1.0f / 127.0f);

    unsigned int* orow = xq4 + (size_t)b * (IN_F / 4);
#pragma unroll
    for (int i = 0; i < 4; ++i) {
      int q0 = (int)rintf(v[i].x * r);
      int q1 = (int)rintf(v[i].y * r);
      int q2 = (int)rintf(v[i].z * r);
      int q3 = (int)rintf(v[i].w * r);
      orow[tid + i * 256] = (unsigned)(q0 & 0xFF) | ((unsigned)(q1 & 0xFF) << 8) |
                            ((unsigned)(q2 & 0xFF) << 16) | ((unsigned)(q3 & 0xFF) << 24);
    }
  } else {
    // ---- W row: dequant + act-order permute + int8 re-quant ----
    const int o = b - M;
    const int4* wp4 = (const int4*)(wp + (size_t)o * (IN_F / 2));
    int4* p4 = (int4*)prow;
#pragma unroll
    for (int i = 0; i < 2; ++i)
      p4[tid + i * 256] = wp4[tid + i * 256];
    if (tid < IN_F / GS) srow[tid] = wsc[o * (IN_F / GS) + tid];
    __syncthreads();

    float m = 0.f;
#pragma unroll
    for (int c = 0; c < 8; ++c) {
      const int p = tid + c * 256;
      const unsigned bb = prow[p];
      const float s = srow[p >> 6];
      const float lo = (float)((int)(bb & 0xFu) - 8);
      const float hi = (float)((int)((bb >> 4) & 0xFu) - 8);
      m = fmaxf(m, fmaxf(fabsf(lo), fabsf(hi)) * s);
    }
    red[tid] = m;
    __syncthreads();
#pragma unroll
    for (int s = 128; s > 0; s >>= 1) {
      if (tid < s) red[tid] = fmaxf(red[tid], red[tid + s]);
      __syncthreads();
    }
    const float wmax = red[0];
    const float r = (wmax > 0.f) ? 127.0f / wmax : 0.f;
    if (tid == 0) sw[o] = wmax * (1.0f / 127.0f);

    unsigned int* orow = wq4 + (size_t)o * (IN_F / 4);
    const int4* inv4 = (const int4*)inv;
#pragma unroll
    for (int c = 0; c < 4; ++c) {
      const int p = tid + c * 256;
      const int4 iv = inv4[p];
      unsigned out = 0;
      const int idx[4] = {iv.x, iv.y, iv.z, iv.w};
#pragma unroll
      for (int e = 0; e < 4; ++e) {
        const int ii = idx[e];
        const unsigned wbits = prow[ii >> 1];
        const int n = (int)((wbits >> ((ii & 1) * 4)) & 0xFu) - 8;
        const float v = (float)n * srow[ii >> 7] * r;
        const int q = (int)rintf(v);
        out |= (unsigned)(q & 0xFF) << (e * 8);
      }
      orow[p] = out;
    }
  }
}

// ---- One K-tile, 4 phases, 2 barriers/tile ----
// Per phase: ds_read frags (buf cur) | issue 2 gloads (buf nxt) | lgkmcnt(0) |
// MFMA. Barriers only at p1-end (after vmcnt(4)) and p3-end (after vmcnt(2)) —
// waves skew within the 2-phase windows so one wave's MFMA hides its SIMD
// partner's ds_reads.
// Staging order for tile t+1: B[0:64),B[64:128) @p0; B[128:192),B[192:256) @p1;
// A[0:64),A[128:192) @p2; A[64:128),A[192:256) @p3.
// Happens-before: A-late chunks (A1,A3) of cur stay in flight across the tile
// boundary; vmcnt(4)@p1 + barrier drains them before their first read (p2).
// vmcnt(2)@p3 + barrier drains B*,A0,A2 of nxt before t+1 p0 reads. Buffer
// overwrite (staging into nxt at p0) is safe: every wave's reads of that buffer
// completed before its previous-tile p3 MFMA (lgkmcnt(0)), upstream of the
// p3-end barrier. LAST tile: no staging, so p1 must use vmcnt(0).
template <bool LAST>
__device__ __forceinline__ void gemm_tile(
    const signed char* Ac, const signed char* Bc,
    signed char* An, signed char* Bn,
    const signed char* a_base, const signed char* b_base, int k0n,
    int wave, int wm, int wn, int l16, int quad, int sxz,
    int growl, int gcolb, i32x4 (&acc)[8][4])
{
  i32x4 bq[4][2];   // B frags cached for the whole tile (read at phase 0)
#pragma unroll
  for (int p = 0; p < 4; ++p) {
    if (p == 0) {
#pragma unroll
      for (int j = 0; j < 4; ++j)
#pragma unroll
        for (int ks = 0; ks < 2; ++ks) {
          const int off = (wn + j * 16 + l16) * BKB + ((ks * 64 + quad * 16) ^ sxz);
          bq[j][ks] = *(const i32x4*)(Bc + off);
        }
    }
    i32x4 aq[2][2];
#pragma unroll
    for (int i = 0; i < 2; ++i)
#pragma unroll
      for (int ks = 0; ks < 2; ++ks) {
        const int off = (wm + p * 32 + i * 16 + l16) * BKB + ((ks * 64 + quad * 16) ^ sxz);
        aq[i][ks] = *(const i32x4*)(Ac + off);
      }
    if (!LAST) {
      if (p == 0) {
        stage_g(Bn, 0, b_base, k0n, wave, growl, gcolb);
        stage_g(Bn, 64, b_base, k0n, wave, growl, gcolb);
      } else if (p == 1) {
        stage_g(Bn, 128, b_base, k0n, wave, growl, gcolb);
        stage_g(Bn, 192, b_base, k0n, wave, growl, gcolb);
      } else if (p == 2) {
        stage_g(An, 0, a_base, k0n, wave, growl, gcolb);
        stage_g(An, 128, a_base, k0n, wave, growl, gcolb);
      } else {
        stage_g(An, 64, a_base, k0n, wave, growl, gcolb);
        stage_g(An, 192, a_base, k0n, wave, growl, gcolb);
      }
    }
    asm volatile("s_waitcnt lgkmcnt(0)" ::: "memory");
    __builtin_amdgcn_sched_barrier(0);   // rule #18: pin MFMA below the wait
    __builtin_amdgcn_s_setprio(1);
#pragma unroll
    for (int i = 0; i < 2; ++i)
#pragma unroll
      for (int j = 0; j < 4; ++j)
#pragma unroll
        for (int ks = 0; ks < 2; ++ks)
          acc[2 * p + i][j] = __builtin_amdgcn_mfma_i32_16x16x64_i8(
              aq[i][ks], bq[j][ks], acc[2 * p + i][j], 0, 0, 0);
    __builtin_amdgcn_s_setprio(0);
    if (p == 1) {
      if (LAST) { asm volatile("s_waitcnt vmcnt(0)" ::: "memory"); }
      else      { asm volatile("s_waitcnt vmcnt(4)" ::: "memory"); }
      __builtin_amdgcn_sched_barrier(0);
      __builtin_amdgcn_s_barrier();
    } else if (p == 3) {
      if (!LAST) { asm volatile("s_waitcnt vmcnt(2)" ::: "memory"); }
      __builtin_amdgcn_sched_barrier(0);
      __builtin_amdgcn_s_barrier();
    }
  }
}

// C[M][N] = xq(i8) * wq(i8)^T scaled by sx[row]*sw[col] + bias.
// 256^2 template, i8 variant: T2 swizzle = G4 3-bit XOR ((row&7)<<4), counted
// vmcnt (T4), setprio (T5), 2 barriers/tile.
__global__ __launch_bounds__(512, 2) void gemm_kernel(
    const signed char* __restrict__ A,
    const signed char* __restrict__ B,
    const float* __restrict__ sx,
    const float* __restrict__ sw,
    const float* __restrict__ bias,
    float* __restrict__ C) {
  __shared__ signed char As[2 * BUFB];  // 64 KB
  __shared__ signed char Bs[2 * BUFB];  // 64 KB

  const int tid  = threadIdx.x;
  const int wave = tid >> 6;
  const int lane = tid & 63;
  const int quad = lane >> 4;
  const int l16  = lane & 15;

  const int bm = blockIdx.y;
  const int bn = blockIdx.x;
  const signed char* a_base = A + (size_t)bm * BM * IN_F;
  const signed char* b_base = B + (size_t)bn * BN * IN_F;

  // per-wave output strip: 128 rows x 64 cols (2M x 4N wave grid)
  const int wm = (wave >> 2) * 128;
  const int wn = (wave & 3) * 64;
  // read-side swizzle: row&7 == l16&7 for all fragment rows (strip offsets are
  // multiples of 16)
  const int sxz = (l16 & 7) << 4;

  // staging source pre-swizzle: lane writes LDS byte d = tid*16 within an 8KB
  // 64-row chunk; logical byte = d ^ ((row&7)<<4) with row = d>>7 = tid>>3.
  const int growl = tid >> 3;                                   // row 0..63
  const int gcolb = ((tid & 7) ^ ((tid >> 3) & 7)) << 4;        // 16B-aligned col

  i32x4 acc[8][4] = {};

  // Prologue: stage tile 0 in steady-state chunk order; counted wait leaves the
  // two late-A chunks in flight (drained by vmcnt(4)+barrier at p1 of tile 0).
  stage_g(Bs, 0, b_base, 0, wave, growl, gcolb);
  stage_g(Bs, 64, b_base, 0, wave, growl, gcolb);
  stage_g(Bs, 128, b_base, 0, wave, growl, gcolb);
  stage_g(Bs, 192, b_base, 0, wave, growl, gcolb);
  stage_g(As, 0, a_base, 0, wave, growl, gcolb);
  stage_g(As, 128, a_base, 0, wave, growl, gcolb);
  stage_g(As, 64, a_base, 0, wave, growl, gcolb);
  stage_g(As, 192, a_base, 0, wave, growl, gcolb);
  asm volatile("s_waitcnt vmcnt(2)" ::: "memory");
  __builtin_amdgcn_sched_barrier(0);
  __builtin_amdgcn_s_barrier();

#pragma unroll 1
  for (int t = 0; t < NT - 1; ++t) {
    const int cur = t & 1;
    const int nxt = cur ^ 1;
    gemm_tile<false>(As + cur * BUFB, Bs + cur * BUFB,
                     As + nxt * BUFB, Bs + nxt * BUFB,
                     a_base, b_base, (t + 1) * BKB,
                     wave, wm, wn, l16, quad, sxz, growl, gcolb, acc);
  }
  gemm_tile<true>(As + ((NT - 1) & 1) * BUFB, Bs + ((NT - 1) & 1) * BUFB,
                  nullptr, nullptr, a_base, b_base, 0,
                  wave, wm, wn, l16, quad, sxz, growl, gcolb, acc);

  // Epilogue: stage scales+bias in LDS (p3-end barrier of LAST tile guarantees
  // all waves' tile reads are complete before we overwrite As)
  float* sxs = (float*)As;          // 256 floats
  float* sws = sxs + BM;            // 256 floats
  float* bsh = sws + BN;            // 256 floats
  if (tid < BM) {
    sxs[tid] = sx[bm * BM + tid];
  } else {
    const int c = tid - BM;
    sws[c] = sw[bn * BN + c];
    bsh[c] = bias[bn * BN + c];
  }
  __syncthreads();

  // C/D layout: col=lane&15, row=quad*4+reg (dtype-independent, m121-m128)
  const int wm_g = bm * BM + wm;
  const int wn_g = bn * BN + wn;
#pragma unroll
  for (int j = 0; j < 4; ++j) {
    const int col_l = wn + j * 16 + l16;
    const float swv = sws[col_l];
    const float bv  = bsh[col_l];
    const int col = wn_g + j * 16 + l16;
#pragma unroll
    for (int i = 0; i < 8; ++i) {
      const int row_l0 = wm + i * 16 + quad * 4;
      const int row0 = wm_g + i * 16 + quad * 4;
#pragma unroll
      for (int r = 0; r < 4; ++r)
        C[(size_t)(row0 + r) * OUT_F + col] =
            (float)acc[i][j][r] * (sxs[row_l0 + r] * swv) + bv;
    }
  }
}

extern "C" void kernel_launch(void* const* d_in, const int* in_sizes, int n_in,
                              void* d_out, int out_size, void* d_ws, size_t ws_size,
                              hipStream_t stream) {
  const float* x    = (const float*)d_in[0];
  const int*   wp   = (const int*)d_in[1];
  const float* wsc  = (const float*)d_in[2];
  const int*   perm = (const int*)d_in[3];
  const float* bias = (const float*)d_in[4];
  float* out = (float*)d_out;

  const int M = in_sizes[0] / IN_F;   // 8192 tokens

  // ws layout: xq [M][IN_F] i8 | wq [OUT_F][IN_F] i8 | sx [M] | sw [OUT_F] | inv [IN_F]
  signed char* xq = (signed char*)d_ws;
  signed char* wq = xq + (size_t)M * IN_F;
  float* sx = (float*)(wq + (size_t)OUT_F * IN_F);
  float* sw = sx + M;
  int* inv = (int*)(sw + OUT_F);

  invperm_kernel<<<IN_F / 256, 256, 0, stream>>>(perm, inv);

  prep_kernel<<<M + OUT_F, 256, 0, stream>>>(
      x, (unsigned int*)xq, sx, wp, wsc, inv, (unsigned int*)wq, sw, M);

  dim3 grid(OUT_F / BN, M / BM);   // (16, 32)
  gemm_kernel<<<grid, 512, 0, stream>>>(xq, wq, sx, sw, bias, out);
}

// Round 4
// 379.361 us; speedup vs baseline: 1.1365x; 1.0075x over previous
//
#include <hip/hip_runtime.h>

#define IN_F 4096
#define OUT_F 4096
#define GS 128

// ---- GEMM geometry: 256x256 tile, BK=128 i8, 8 waves (2M x 4N), 512 thr ----
#define BM 256
#define BN 256
#define BKB 128                 // K-bytes (= i8 elements) per K-tile
#define NT (IN_F / BKB)         // 32 K-tiles
#define BUFB (BM * BKB)         // 32768 B per buffer per matrix

typedef int i32x4 __attribute__((ext_vector_type(4)));

typedef __attribute__((address_space(1))) void void_g;
typedef __attribute__((address_space(3))) void void_l;

// Async global->LDS, 16B per lane. LDS dest = wave-uniform base + lane*16.
__device__ __forceinline__ void async_copy16(void* lds, const void* g) {
  __builtin_amdgcn_global_load_lds((const void_g*)g, (void_l*)lds, 16, 0, 0);
}

// Stage one block-wide 8KB chunk (64 rows x 128B) of `mat` K-tile k0 into LDS.
// LDS write is linear (lane d = tid*16); global source is pre-swizzled with the
// G4 3-bit XOR (byte ^= (row&7)<<4) so swizzled READS see logical data.
__device__ __forceinline__ void stage_g(signed char* region, int rowbase,
                                        const signed char* mat, int k0,
                                        int wave, int growl, int gcolb) {
  async_copy16(region + rowbase * BKB + wave * 1024,
               mat + (size_t)(rowbase + growl) * IN_F + k0 + gcolb);
}

// inv[perm[i]] = i
__global__ void invperm_kernel(const int* __restrict__ perm, int* __restrict__ inv) {
  int i = blockIdx.x * blockDim.x + threadIdx.x;
  inv[perm[i]] = i;
}

// Fused pre-processing: blocks [0,M) per-token int8 x-quant; blocks [M,M+OUT_F)
// dequant+perm+quant of W rows.
__global__ __launch_bounds__(256) void prep_kernel(
    const float* __restrict__ x,
    unsigned int* __restrict__ xq4,   // [M][IN_F/4]
    float* __restrict__ sx,           // [M]
    const int* __restrict__ wp,      // [OUT_F][IN_F/2]
    const float* __restrict__ wsc,   // [OUT_F][IN_F/GS]
    const int* __restrict__ inv,     // [IN_F]
    unsigned int* __restrict__ wq4,  // [OUT_F][IN_F/4]
    float* __restrict__ sw,          // [OUT_F]
    int M)
{
  __shared__ unsigned int prow[IN_F / 2];  // 8 KB (dequant path)
  __shared__ float srow[IN_F / GS];
  __shared__ float red[256];
  const int tid = threadIdx.x;
  const int b = blockIdx.x;

  if (b < M) {
    // ---- per-token x quantization ----
    const float4* x4 = (const float4*)(x + (size_t)b * IN_F);
    float4 v[4];
    float m = 0.f;
#pragma unroll
    for (int i = 0; i < 4; ++i) {
      v[i] = x4[tid + i * 256];
      m = fmaxf(m, fmaxf(fmaxf(fabsf(v[i].x), fabsf(v[i].y)),
                         fmaxf(fabsf(v[i].z), fabsf(v[i].w))));
    }
    red[tid] = m;
    __syncthreads();
#pragma unroll
    for (int s = 128; s > 0; s >>= 1) {
      if (tid < s) red[tid] = fmaxf(red[tid], red[tid + s]);
      __syncthreads();
    }
    const float mx = red[0];
    const float r = 127.0f / mx;
    if (tid == 0) sx[b] = mx * (1.0f / 127.0f);

    unsigned int* orow = xq4 + (size_t)b * (IN_F / 4);
#pragma unroll
    for (int i = 0; i < 4; ++i) {
      int q0 = (int)rintf(v[i].x * r);
      int q1 = (int)rintf(v[i].y * r);
      int q2 = (int)rintf(v[i].z * r);
      int q3 = (int)rintf(v[i].w * r);
      orow[tid + i * 256] = (unsigned)(q0 & 0xFF) | ((unsigned)(q1 & 0xFF) << 8) |
                            ((unsigned)(q2 & 0xFF) << 16) | ((unsigned)(q3 & 0xFF) << 24);
    }
  } else {
    // ---- W row: dequant + act-order permute + int8 re-quant ----
    const int o = b - M;
    const int4* wp4 = (const int4*)(wp + (size_t)o * (IN_F / 2));
    int4* p4 = (int4*)prow;
#pragma unroll
    for (int i = 0; i < 2; ++i)
      p4[tid + i * 256] = wp4[tid + i * 256];
    if (tid < IN_F / GS) srow[tid] = wsc[o * (IN_F / GS) + tid];
    __syncthreads();

    float m = 0.f;
#pragma unroll
    for (int c = 0; c < 8; ++c) {
      const int p = tid + c * 256;
      const unsigned bb = prow[p];
      const float s = srow[p >> 6];
      const float lo = (float)((int)(bb & 0xFu) - 8);
      const float hi = (float)((int)((bb >> 4) & 0xFu) - 8);
      m = fmaxf(m, fmaxf(fabsf(lo), fabsf(hi)) * s);
    }
    red[tid] = m;
    __syncthreads();
#pragma unroll
    for (int s = 128; s > 0; s >>= 1) {
      if (tid < s) red[tid] = fmaxf(red[tid], red[tid + s]);
      __syncthreads();
    }
    const float wmax = red[0];
    const float r = (wmax > 0.f) ? 127.0f / wmax : 0.f;
    if (tid == 0) sw[o] = wmax * (1.0f / 127.0f);

    unsigned int* orow = wq4 + (size_t)o * (IN_F / 4);
    const int4* inv4 = (const int4*)inv;
#pragma unroll
    for (int c = 0; c < 4; ++c) {
      const int p = tid + c * 256;
      const int4 iv = inv4[p];
      unsigned out = 0;
      const int idx[4] = {iv.x, iv.y, iv.z, iv.w};
#pragma unroll
      for (int e = 0; e < 4; ++e) {
        const int ii = idx[e];
        const unsigned wbits = prow[ii >> 1];
        const int n = (int)((wbits >> ((ii & 1) * 4)) & 0xFu) - 8;
        const float v = (float)n * srow[ii >> 7] * r;
        const int q = (int)rintf(v);
        out |= (unsigned)(q & 0xFF) << (e * 8);
      }
      orow[p] = out;
    }
  }
}

// ---- One K-tile, 4 phases, m201 sandwich barriers (2 per phase) ----
// Per phase: {ds_read frags (buf cur); issue 2 gloads (buf nxt); s_barrier;
// lgkmcnt(0); setprio(1); 16 MFMA; setprio(0); [counted vmcnt @p1/p3];
// s_barrier}. The pre-MFMA barrier absorbs LDS read latency in barrier-arrival
// skew (lgkmcnt(0) is then near-free), and the post-MFMA barrier keeps the
// 2 waves/SIMD in lockstep alternation of LDS and matrix pipes (m201: 62%
// MfmaUtil on byte-identical bf16 geometry; our round-3 2-barrier variant
// drifted and serialized at 42%).
// Staging order for tile t+1: B[0:64),B[64:128) @p0; B[128:192),B[192:256) @p1;
// A[0:64),A[128:192) @p2; A[64:128),A[192:256) @p3.
// Happens-before (counted drains, never 0 in main loop):
//  - p1-end vmcnt(4): outstanding = 2 carried (cur A64,A192 staged at prev p3)
//    + 4 B-chunks of nxt; waits the 2 oldest = carried pair, which p2 reads
//    (rows 64-95 in A[64:128)). Barrier publishes to all waves.
//  - p3-end vmcnt(2): outstanding = 4 B + 4 A of nxt minus... = drains B0-3 and
//    A[0:64),A[128:192) — everything t+1 reads at p0/p1 — leaving the 2 late-A
//    chunks in flight across the boundary. Barrier publishes.
//  - Buffer overwrite (stage into nxt at p0) is safe: all waves' reads of nxt's
//    previous contents finished before their prior-tile p3 MFMA (lgkmcnt(0)),
//    upstream of the p3-end barrier.
//  - LAST tile: no staging; p1 drains the 2 carried chunks with vmcnt(0).
template <bool LAST>
__device__ __forceinline__ void gemm_tile(
    const signed char* Ac, const signed char* Bc,
    signed char* An, signed char* Bn,
    const signed char* a_base, const signed char* b_base, int k0n,
    int wave, int wm, int wn, int l16, int quad, int sxz,
    int growl, int gcolb, i32x4 (&acc)[8][4])
{
  i32x4 bq[4][2];   // B frags cached for the whole tile (read at phase 0)
#pragma unroll
  for (int p = 0; p < 4; ++p) {
    if (p == 0) {
#pragma unroll
      for (int j = 0; j < 4; ++j)
#pragma unroll
        for (int ks = 0; ks < 2; ++ks) {
          const int off = (wn + j * 16 + l16) * BKB + ((ks * 64 + quad * 16) ^ sxz);
          bq[j][ks] = *(const i32x4*)(Bc + off);
        }
    }
    i32x4 aq[2][2];
#pragma unroll
    for (int i = 0; i < 2; ++i)
#pragma unroll
      for (int ks = 0; ks < 2; ++ks) {
        const int off = (wm + p * 32 + i * 16 + l16) * BKB + ((ks * 64 + quad * 16) ^ sxz);
        aq[i][ks] = *(const i32x4*)(Ac + off);
      }
    if (!LAST) {
      if (p == 0) {
        stage_g(Bn, 0, b_base, k0n, wave, growl, gcolb);
        stage_g(Bn, 64, b_base, k0n, wave, growl, gcolb);
      } else if (p == 1) {
        stage_g(Bn, 128, b_base, k0n, wave, growl, gcolb);
        stage_g(Bn, 192, b_base, k0n, wave, growl, gcolb);
      } else if (p == 2) {
        stage_g(An, 0, a_base, k0n, wave, growl, gcolb);
        stage_g(An, 128, a_base, k0n, wave, growl, gcolb);
      } else {
        stage_g(An, 64, a_base, k0n, wave, growl, gcolb);
        stage_g(An, 192, a_base, k0n, wave, growl, gcolb);
      }
    }
    __builtin_amdgcn_s_barrier();        // sandwich start: absorb ds latency
    asm volatile("s_waitcnt lgkmcnt(0)" ::: "memory");
    __builtin_amdgcn_sched_barrier(0);   // rule #18: pin MFMA below the wait
    __builtin_amdgcn_s_setprio(1);
#pragma unroll
    for (int i = 0; i < 2; ++i)
#pragma unroll
      for (int j = 0; j < 4; ++j)
#pragma unroll
        for (int ks = 0; ks < 2; ++ks)
          acc[2 * p + i][j] = __builtin_amdgcn_mfma_i32_16x16x64_i8(
              aq[i][ks], bq[j][ks], acc[2 * p + i][j], 0, 0, 0);
    __builtin_amdgcn_s_setprio(0);
    if (p == 1) {
      if (LAST) { asm volatile("s_waitcnt vmcnt(0)" ::: "memory"); }
      else      { asm volatile("s_waitcnt vmcnt(4)" ::: "memory"); }
      __builtin_amdgcn_sched_barrier(0);
    } else if (p == 3 && !LAST) {
      asm volatile("s_waitcnt vmcnt(2)" ::: "memory");
      __builtin_amdgcn_sched_barrier(0);
    }
    __builtin_amdgcn_s_barrier();        // sandwich end
  }
}

// C[M][N] = xq(i8) * wq(i8)^T scaled by sx[row]*sw[col] + bias.
// 256^2 m201 template, i8 variant: T2 swizzle = G4 3-bit XOR ((row&7)<<4),
// counted vmcnt (T4), setprio (T5), sandwich barriers (T3 structure).
__global__ __launch_bounds__(512, 2) void gemm_kernel(
    const signed char* __restrict__ A,
    const signed char* __restrict__ B,
    const float* __restrict__ sx,
    const float* __restrict__ sw,
    const float* __restrict__ bias,
    float* __restrict__ C) {
  __shared__ signed char As[2 * BUFB];  // 64 KB
  __shared__ signed char Bs[2 * BUFB];  // 64 KB

  const int tid  = threadIdx.x;
  const int wave = tid >> 6;
  const int lane = tid & 63;
  const int quad = lane >> 4;
  const int l16  = lane & 15;

  const int bm = blockIdx.y;
  const int bn = blockIdx.x;
  const signed char* a_base = A + (size_t)bm * BM * IN_F;
  const signed char* b_base = B + (size_t)bn * BN * IN_F;

  // per-wave output strip: 128 rows x 64 cols (2M x 4N wave grid)
  const int wm = (wave >> 2) * 128;
  const int wn = (wave & 3) * 64;
  // read-side swizzle: row&7 == l16&7 for all fragment rows (strip offsets are
  // multiples of 16)
  const int sxz = (l16 & 7) << 4;

  // staging source pre-swizzle: lane writes LDS byte d = tid*16 within an 8KB
  // 64-row chunk; logical byte = d ^ ((row&7)<<4) with row = d>>7 = tid>>3.
  const int growl = tid >> 3;                                   // row 0..63
  const int gcolb = ((tid & 7) ^ ((tid >> 3) & 7)) << 4;        // 16B-aligned col

  i32x4 acc[8][4] = {};

  // Prologue: stage tile 0 in steady-state chunk order; counted wait leaves the
  // two late-A chunks in flight (drained by vmcnt(4) at p1 of tile 0).
  stage_g(Bs, 0, b_base, 0, wave, growl, gcolb);
  stage_g(Bs, 64, b_base, 0, wave, growl, gcolb);
  stage_g(Bs, 128, b_base, 0, wave, growl, gcolb);
  stage_g(Bs, 192, b_base, 0, wave, growl, gcolb);
  stage_g(As, 0, a_base, 0, wave, growl, gcolb);
  stage_g(As, 128, a_base, 0, wave, growl, gcolb);
  stage_g(As, 64, a_base, 0, wave, growl, gcolb);
  stage_g(As, 192, a_base, 0, wave, growl, gcolb);
  asm volatile("s_waitcnt vmcnt(2)" ::: "memory");
  __builtin_amdgcn_sched_barrier(0);
  __builtin_amdgcn_s_barrier();

#pragma unroll 1
  for (int t = 0; t < NT - 1; ++t) {
    const int cur = t & 1;
    const int nxt = cur ^ 1;
    gemm_tile<false>(As + cur * BUFB, Bs + cur * BUFB,
                     As + nxt * BUFB, Bs + nxt * BUFB,
                     a_base, b_base, (t + 1) * BKB,
                     wave, wm, wn, l16, quad, sxz, growl, gcolb, acc);
  }
  gemm_tile<true>(As + ((NT - 1) & 1) * BUFB, Bs + ((NT - 1) & 1) * BUFB,
                  nullptr, nullptr, a_base, b_base, 0,
                  wave, wm, wn, l16, quad, sxz, growl, gcolb, acc);

  // Epilogue: stage scales+bias in LDS (p3-end barrier of LAST tile guarantees
  // all waves' tile reads are complete before we overwrite As)
  float* sxs = (float*)As;          // 256 floats
  float* sws = sxs + BM;            // 256 floats
  float* bsh = sws + BN;            // 256 floats
  if (tid < BM) {
    sxs[tid] = sx[bm * BM + tid];
  } else {
    const int c = tid - BM;
    sws[c] = sw[bn * BN + c];
    bsh[c] = bias[bn * BN + c];
  }
  __syncthreads();

  // C/D layout: col=lane&15, row=quad*4+reg (dtype-independent, m121-m128)
  const int wm_g = bm * BM + wm;
  const int wn_g = bn * BN + wn;
#pragma unroll
  for (int j = 0; j < 4; ++j) {
    const int col_l = wn + j * 16 + l16;
    const float swv = sws[col_l];
    const float bv  = bsh[col_l];
    const int col = wn_g + j * 16 + l16;
#pragma unroll
    for (int i = 0; i < 8; ++i) {
      const int row_l0 = wm + i * 16 + quad * 4;
      const int row0 = wm_g + i * 16 + quad * 4;
#pragma unroll
      for (int r = 0; r < 4; ++r)
        C[(size_t)(row0 + r) * OUT_F + col] =
            (float)acc[i][j][r] * (sxs[row_l0 + r] * swv) + bv;
    }
  }
}

extern "C" void kernel_launch(void* const* d_in, const int* in_sizes, int n_in,
                              void* d_out, int out_size, void* d_ws, size_t ws_size,
                              hipStream_t stream) {
  const float* x    = (const float*)d_in[0];
  const int*   wp   = (const int*)d_in[1];
  const float* wsc  = (const float*)d_in[2];
  const int*   perm = (const int*)d_in[3];
  const float* bias = (const float*)d_in[4];
  float* out = (float*)d_out;

  const int M = in_sizes[0] / IN_F;   // 8192 tokens

  // ws layout: xq [M][IN_F] i8 | wq [OUT_F][IN_F] i8 | sx [M] | sw [OUT_F] | inv [IN_F]
  signed char* xq = (signed char*)d_ws;
  signed char* wq = xq + (size_t)M * IN_F;
  float* sx = (float*)(wq + (size_t)OUT_F * IN_F);
  float* sw = sx + M;
  int* inv = (int*)(sw + OUT_F);

  invperm_kernel<<<IN_F / 256, 256, 0, stream>>>(perm, inv);

  prep_kernel<<<M + OUT_F, 256, 0, stream>>>(
      x, (unsigned int*)xq, sx, wp, wsc, inv, (unsigned int*)wq, sw, M);

  dim3 grid(OUT_F / BN, M / BM);   // (16, 32)
  gemm_kernel<<<grid, 512, 0, stream>>>(xq, wq, sx, sw, bias, out);
}